// Round 10
// baseline (512.099 us; speedup 1.0000x reference)
//
#include <hip/hip_runtime.h>
#include <hip/hip_cooperative_groups.h>

// SelfAttentiveLBLBiLM on MI355X — round 10: cooperative mega-kernel, made
// launch-proof. r9's coop launch was silently rejected (LDS 34816B -> 1
// block/CU under the runtime occupancy model -> grid 512 too large). Now:
//  - static LDS exactly 32768B (proj rel-add stage ld 136 -> 128)
//  - grid sized from hipOccupancyMaxActiveBlocksPerMultiprocessor (host-side,
//    capture-safe); persistent loops work at any resident grid size
//  - checked fallback to the equivalent 6-dispatch path on launch error
// Math identical to r7 (absmax 0.109375).

namespace cg = cooperative_groups;

#define B_ 8
#define S_ 1024
#define D_ 512
#define H_ 8
#define DK_ 64
#define WIDTH_ 8
#define S2_ 1040
#define NHW_ 2

typedef short bf16x8 __attribute__((ext_vector_type(8)));
typedef float f32x4 __attribute__((ext_vector_type(4)));

__device__ __forceinline__ float us2f(unsigned short u) {
  union { unsigned int i; float f; } c; c.i = ((unsigned int)u) << 16; return c.f;
}
__device__ __forceinline__ unsigned short f2us(float f) {
  union { float f; unsigned int i; } c; c.f = f;
  unsigned int x = c.i;
  return (unsigned short)((x + 0x7fffu + ((x >> 16) & 1u)) >> 16);
}
__device__ __forceinline__ unsigned int pack2(float a, float b) {
  return (unsigned int)f2us(a) | ((unsigned int)f2us(b) << 16);
}
__device__ __forceinline__ void async16(const void* g, void* l) {
  __builtin_amdgcn_global_load_lds(
      (const __attribute__((address_space(1))) void*)g,
      (__attribute__((address_space(3))) void*)l, 16, 0, 0);
}
__device__ __forceinline__ void unpack8(uint4 u, float* f) {
  unsigned int w[4] = {u.x, u.y, u.z, u.w};
  #pragma unroll
  for (int c = 0; c < 4; ++c) {
    union { unsigned int i; float g; } lo, hi;
    lo.i = w[c] << 16;
    hi.i = w[c] & 0xffff0000u;
    f[2 * c] = lo.g;
    f[2 * c + 1] = hi.g;
  }
}

struct Params {
  const float *x, *lpad, *rpad, *lW, *rW, *lb, *rb, *lhwW, *rhwW,
              *lhwb, *rhwb, *lw, *rw;
  float* out;
  unsigned short *nin, *qkv, *ctx, *hwx, *hwy, *WTall, *WTp, *hWT;
  float* qkvbias;
};

// ---------------------------------------------------------------------------
// Shared K=512 MFMA core: 128x128 tile at (bm,bn); BK=64, XOR-swizzled LDS.
__device__ __forceinline__ void kloop512(
    const unsigned short* __restrict__ A, const unsigned short* __restrict__ BT,
    int bm, int bn, int tid, unsigned short* As, unsigned short* Bs,
    f32x4 acc[4][4])
{
  const int K = 512;
  const int w = tid >> 6;
  const int l = tid & 63;
  const int wrow = (w >> 1) * 64;
  const int wcol = (w & 1) * 64;

  const int lr = l >> 3;
  const int sk = (((l & 7) ^ lr) & 7) * 8;
  const unsigned short* Ap = A + (size_t)(bm + w * 8 + lr) * K + sk;
  const unsigned short* Bp = BT + (size_t)(bn + w * 8 + lr) * K + sk;
  unsigned short* lA = &As[w * 512];
  unsigned short* lB = &Bs[w * 512];
  const size_t K32 = (size_t)32 * K;

  const int fl = l & 15;
  const int fq = l >> 4;
  const int fx = fl & 7;

  #pragma unroll
  for (int mi = 0; mi < 4; ++mi)
    #pragma unroll
    for (int ni = 0; ni < 4; ++ni) acc[mi][ni] = (f32x4){0.f, 0.f, 0.f, 0.f};

  for (int k0 = 0; k0 < K; k0 += 64) {
    #pragma unroll
    for (int r = 0; r < 4; ++r) {
      async16(Ap + k0 + r * K32, lA + r * 2048);
      async16(Bp + k0 + r * K32, lB + r * 2048);
    }
    __syncthreads();
    #pragma unroll
    for (int s = 0; s < 2; ++s) {
      bf16x8 af[4], bfr[4];
      #pragma unroll
      for (int mi = 0; mi < 4; ++mi)
        af[mi] = *reinterpret_cast<const bf16x8*>(
            &As[(wrow + mi * 16 + fl) * 64 + (((s * 4 + fq) ^ fx) * 8)]);
      #pragma unroll
      for (int ni = 0; ni < 4; ++ni)
        bfr[ni] = *reinterpret_cast<const bf16x8*>(
            &Bs[(wcol + ni * 16 + fl) * 64 + (((s * 4 + fq) ^ fx) * 8)]);
      #pragma unroll
      for (int mi = 0; mi < 4; ++mi)
        #pragma unroll
        for (int ni = 0; ni < 4; ++ni)
          acc[mi][ni] = __builtin_amdgcn_mfma_f32_16x16x32_bf16(
              af[mi], bfr[ni], acc[mi][ni], 0, 0, 0);
    }
    __syncthreads();
  }
}

// ---------------------------------------------------------------------------
// Phase 0: prep virtual block (0..6187).
__device__ __forceinline__ void prep_block(
    int bx, int tid, const Params& p, unsigned short* smemu)
{
  float (*tile)[33] = reinterpret_cast<float (*)[33]>(smemu);
  const size_t DD = (size_t)D_ * D_;
  int tx = tid & 31, ty = tid >> 5;

  if (bx < 2048) {                     // attn weight transpose
    int sl = bx >> 8, rem = bx & 255;
    int side = sl >> 2, slice = sl & 3;
    int c0 = (rem & 15) * 32, r0 = (rem >> 4) * 32;
    const float* src = (side ? p.rW : p.lW) + (size_t)slice * DD;
    unsigned short* dst = (slice < 3)
        ? p.WTall + (size_t)(side * 3 + slice) * DD
        : p.WTp + (size_t)side * DD;
    #pragma unroll
    for (int i = 0; i < 4; ++i)
      tile[ty + i * 8][tx] = src[(size_t)(r0 + ty + i * 8) * D_ + c0 + tx];
    __syncthreads();
    #pragma unroll
    for (int i = 0; i < 4; ++i)
      dst[(size_t)(c0 + ty + i * 8) * D_ + r0 + tx] = f2us(tile[tx][ty + i * 8]);
    __syncthreads();
  } else if (bx < 4096) {              // hw transpose + interleave
    int idx = bx - 2048;
    int sl = idx >> 9, rem = idx & 511;
    int c0 = (rem & 31) * 32, r0 = (rem >> 5) * 32;
    const float* src = ((sl >> 1) ? p.rhwW : p.lhwW) + (size_t)(sl & 1) * 512 * 1024;
    unsigned short* dst = p.hWT + (size_t)sl * 1024 * 512;
    #pragma unroll
    for (int i = 0; i < 4; ++i)
      tile[ty + i * 8][tx] = src[(size_t)(r0 + ty + i * 8) * 1024 + c0 + tx];
    __syncthreads();
    #pragma unroll
    for (int i = 0; i < 4; ++i) {
      int c = c0 + ty + i * 8;
      int q = (2 * ((c & 511) >> 4) + (c >= 512 ? 1 : 0)) * 16 + (c & 15);
      dst[(size_t)q * 512 + r0 + tx] = f2us(tile[tx][ty + i * 8]);
    }
    __syncthreads();
  } else {                             // build new_in + bias tail (no LDS)
    int gid = (bx - 4096) * 256 + tid;
    const int NTH = B_ * S2_ * 64;
    if (gid >= NTH) {
      int t = gid - NTH;
      if (t < 1536) p.qkvbias[t] = p.lb[t];
      else if (t < 3072) p.qkvbias[t] = p.rb[t - 1536];
    } else {
      int c8 = (gid & 63) << 3;
      int row = gid >> 6;
      int b = row / S2_;
      int t = row - b * S2_;
      const float* src;
      if (t < WIDTH_)            src = p.lpad + (size_t)t * D_ + c8;
      else if (t >= S_ + WIDTH_) src = p.rpad + (size_t)(t - S_ - WIDTH_) * D_ + c8;
      else                       src = p.x + ((size_t)b * S_ + (t - WIDTH_)) * D_ + c8;
      float4 a = *reinterpret_cast<const float4*>(src);
      float4 c = *reinterpret_cast<const float4*>(src + 4);
      uint4 o;
      o.x = pack2(a.x, a.y); o.y = pack2(a.z, a.w);
      o.z = pack2(c.x, c.y); o.w = pack2(c.z, c.w);
      *reinterpret_cast<uint4*>(p.nin + (size_t)row * D_ + c8) = o;
    }
  }
}

// ---------------------------------------------------------------------------
// Phase 1: QKV tile (bx 0..23, by 0..64), direct-store epilogue.
__device__ __forceinline__ void qkv_tile(
    int bx, int by, int tid, const Params& p, unsigned short* smemu)
{
  const int N = 3072;
  const int bm = by * 128, bn = bx * 128;
  const int l = tid & 63;
  const int w = tid >> 6;
  const int wrow = (w >> 1) * 64;
  const int wcol = (w & 1) * 64;
  const int fl = l & 15;

  f32x4 acc[4][4];
  kloop512(p.nin, p.WTall, bm, bn, tid, smemu, smemu + 8192, acc);

  float bv[4];
  #pragma unroll
  for (int ni = 0; ni < 4; ++ni) bv[ni] = p.qkvbias[bn + wcol + ni * 16 + fl];
  const int rbase = (l >> 4) * 4;
  #pragma unroll
  for (int mi = 0; mi < 4; ++mi) {
    #pragma unroll
    for (int r = 0; r < 4; ++r) {
      int row = bm + wrow + mi * 16 + rbase + r;
      unsigned short* Cp = p.qkv + (size_t)row * N + bn + wcol + fl;
      #pragma unroll
      for (int ni = 0; ni < 4; ++ni)
        Cp[ni * 16] = f2us(acc[mi][ni][r] + bv[ni]);
    }
  }
}

// ---------------------------------------------------------------------------
// Phase 2: attention virtual block (0..4095); wave = (dir,b,s).
__device__ __forceinline__ void attn_block(
    int bx, int tid, const Params& p)
{
  int wid = (bx * 256 + tid) >> 6;
  int lane = tid & 63;
  int s = wid & (S_ - 1);
  int b = (wid >> 10) & (B_ - 1);
  int dir = wid >> 13;
  int i = s + WIDTH_;

  const size_t base = (size_t)b * S2_ * 3072 + dir * 1536;
  const int c0 = lane * 8;

  float qf[8];
  unpack8(*reinterpret_cast<const uint4*>(p.qkv + base + (size_t)i * 3072 + c0), qf);

  float sc[10];
  float mx = -1e30f;
  #pragma unroll
  for (int t = 0; t < 10; ++t) {
    int j = (dir == 0) ? (i - 9 + t) : (i + t);
    float sv = -1e30f;
    if (j >= 0 && j < S2_) {
      float kf[8];
      unpack8(*reinterpret_cast<const uint4*>(
          p.qkv + base + (size_t)j * 3072 + 512 + c0), kf);
      float pr = qf[0] * kf[0];
      #pragma unroll
      for (int e = 1; e < 8; ++e) pr += qf[e] * kf[e];
      pr += __shfl_xor(pr, 1);
      pr += __shfl_xor(pr, 2);
      pr += __shfl_xor(pr, 4);
      sv = pr * 0.125f;
    }
    sc[t] = sv;
    mx = fmaxf(mx, sv);
  }

  float denom = 0.f;
  #pragma unroll
  for (int t = 0; t < 10; ++t) {
    sc[t] = (sc[t] > -1e29f) ? __expf(sc[t] - mx) : 0.f;
    denom += sc[t];
  }
  float inv = 1.f / denom;

  float acc[8] = {0.f, 0.f, 0.f, 0.f, 0.f, 0.f, 0.f, 0.f};
  #pragma unroll
  for (int t = 0; t < 10; ++t) {
    int j = (dir == 0) ? (i - 9 + t) : (i + t);
    if (j >= 0 && j < S2_) {
      float vf[8];
      unpack8(*reinterpret_cast<const uint4*>(
          p.qkv + base + (size_t)j * 3072 + 1024 + c0), vf);
      float pr = sc[t];
      #pragma unroll
      for (int e = 0; e < 8; ++e) acc[e] += pr * vf[e];
    }
  }

  uint4 o;
  o.x = pack2(acc[0] * inv, acc[1] * inv);
  o.y = pack2(acc[2] * inv, acc[3] * inv);
  o.z = pack2(acc[4] * inv, acc[5] * inv);
  o.w = pack2(acc[6] * inv, acc[7] * inv);
  *reinterpret_cast<uint4*>(
      p.ctx + (((size_t)dir * B_ + b) * S_ + s) * D_ + c0) = o;
}

// ---------------------------------------------------------------------------
// Phase 3: proj tile (bx 0..3, by 0..63, z side) + staged rel-add epilogue.
// Stage tile at ld=128 (reuses the 32KB staging region exactly).
__device__ __forceinline__ void proj_tile(
    int bx, int by, int z, int tid, const Params& p, unsigned short* smemu)
{
  const size_t MS = (size_t)B_ * S_ * D_;
  const unsigned short* A = p.ctx + (size_t)z * MS;
  const unsigned short* BT = p.WTp + (size_t)z * 512 * 512;
  const float* bias = (z ? p.rb : p.lb) + 3 * D_;
  const float* wrel = z ? p.rw : p.lw;
  const int off = z * WIDTH_;
  const int bm = by * 128, bn = bx * 128;
  const int l = tid & 63;
  const int w = tid >> 6;
  const int wrow = (w >> 1) * 64;
  const int wcol = (w & 1) * 64;
  const int fl = l & 15;

  f32x4 acc[4][4];
  kloop512(A, BT, bm, bn, tid, smemu, smemu + 8192, acc);

  float bv[4];
  #pragma unroll
  for (int ni = 0; ni < 4; ++ni) bv[ni] = bias[bn + wcol + ni * 16 + fl];
  const int rbase = (l >> 4) * 4;
  #pragma unroll
  for (int mi = 0; mi < 4; ++mi)
    #pragma unroll
    for (int r = 0; r < 4; ++r)
      #pragma unroll
      for (int ni = 0; ni < 4; ++ni)
        smemu[(wrow + mi * 16 + rbase + r) * 128 + wcol + ni * 16 + fl] =
            f2us(acc[mi][ni][r] + bv[ni]);
  __syncthreads();

  const int trow = tid >> 4;
  const int tcol = (tid & 15) * 8;
  float wj[9];
  #pragma unroll
  for (int j = 0; j < 9; ++j) wj[j] = wrel[j];
  #pragma unroll
  for (int i = 0; i < 8; ++i) {
    int r = trow + i * 16;
    int gr = bm + r;
    int b = gr >> 10, s = gr & (S_ - 1);
    float a8[8];
    unpack8(*reinterpret_cast<const uint4*>(&smemu[r * 128 + tcol]), a8);
    const unsigned short* np =
        p.nin + ((size_t)b * S2_ + off + s) * D_ + bn + tcol;
    #pragma unroll
    for (int j = 0; j < 9; ++j) {
      float nf[8];
      unpack8(*reinterpret_cast<const uint4*>(np + (size_t)j * D_), nf);
      #pragma unroll
      for (int e = 0; e < 8; ++e) a8[e] += wj[j] * nf[e];
    }
    uint4 o;
    o.x = pack2(a8[0], a8[1]); o.y = pack2(a8[2], a8[3]);
    o.z = pack2(a8[4], a8[5]); o.w = pack2(a8[6], a8[7]);
    *reinterpret_cast<uint4*>(
        p.hwx + (size_t)z * MS + (size_t)gr * D_ + bn + tcol) = o;
  }
  __syncthreads();
}

// ---------------------------------------------------------------------------
// Phase 4/5: highway tile, fused gate, direct-store epilogue.
template <bool FINAL>
__device__ __forceinline__ void hw_tile(
    int bx, int by, int z, int tid, const Params& p, unsigned short* smemu)
{
  const size_t MS = (size_t)B_ * S_ * D_;
  const size_t LHW = (size_t)1024 * 512;
  const unsigned short* A = (FINAL ? p.hwy : p.hwx) + (size_t)z * MS;
  const unsigned short* BT = p.hWT + (size_t)z * 2 * LHW + (FINAL ? LHW : 0);
  const float* bias = (z ? p.rhwb : p.lhwb) + (FINAL ? 1024 : 0);
  const int bm = by * 128, bn = bx * 128;
  const int l = tid & 63;
  const int w = tid >> 6;
  const int wcol = (w & 1) * 64;
  const int wrow = (w >> 1) * 64;
  const int fl = l & 15;

  f32x4 acc[4][4];
  kloop512(A, BT, bm, bn, tid, smemu, smemu + 8192, acc);

  const int ocb = ((bn + wcol) >> 1) + fl;
  float bnl[2], bg[2];
  #pragma unroll
  for (int pp = 0; pp < 2; ++pp) {
    bnl[pp] = bias[ocb + pp * 16];
    bg[pp]  = bias[512 + ocb + pp * 16];
  }

  const int rbase = (l >> 4) * 4;
  #pragma unroll
  for (int mi = 0; mi < 4; ++mi) {
    #pragma unroll
    for (int r = 0; r < 4; ++r) {
      int row = bm + wrow + mi * 16 + rbase + r;
      #pragma unroll
      for (int pp = 0; pp < 2; ++pp) {
        int oc = ocb + pp * 16;
        float nl = fmaxf(acc[mi][2 * pp][r] + bnl[pp], 0.f);
        float g  = 1.f / (1.f + __expf(-(acc[mi][2 * pp + 1][r] + bg[pp])));
        float xv = us2f(A[(size_t)row * 512 + oc]);
        float res = g * xv + (1.f - g) * nl;
        if (FINAL) p.out[(size_t)row * 1024 + z * 512 + oc] = res;
        else       p.hwy[(size_t)z * MS + (size_t)row * 512 + oc] = f2us(res);
      }
    }
  }
}

// ---------------------------------------------------------------------------
// Cooperative mega-kernel: static LDS exactly 32768 B.
__global__ __launch_bounds__(256, 2) void k_mega(Params p)
{
  __shared__ unsigned short smem[16384];
  cg::grid_group grid = cg::this_grid();
  const int tid = threadIdx.x;
  const int bid = blockIdx.x;
  const int nb = gridDim.x;

  for (int vb = bid; vb < 6188; vb += nb) prep_block(vb, tid, p, smem);
  grid.sync();
  for (int t = bid; t < 1560; t += nb) qkv_tile(t % 24, t / 24, tid, p, smem);
  grid.sync();
  for (int vb = bid; vb < 4096; vb += nb) attn_block(vb, tid, p);
  grid.sync();
  for (int t = bid; t < 512; t += nb)
    proj_tile(t & 3, (t >> 2) & 63, t >> 8, tid, p, smem);
  grid.sync();
  for (int t = bid; t < 1024; t += nb)
    hw_tile<false>(t & 7, (t >> 3) & 63, t >> 9, tid, p, smem);
  grid.sync();
  for (int t = bid; t < 1024; t += nb)
    hw_tile<true>(t & 7, (t >> 3) & 63, t >> 9, tid, p, smem);
}

// ---------------------------------------------------------------------------
// Fallback wrappers (6-dispatch path; identical math).
__global__ __launch_bounds__(256) void k_prep_f(Params p) {
  __shared__ unsigned short smem[4224];
  prep_block(blockIdx.x, threadIdx.x, p, smem);
}
__global__ __launch_bounds__(256) void k_qkv_f(Params p) {
  __shared__ unsigned short smem[16384];
  qkv_tile(blockIdx.x, blockIdx.y, threadIdx.x, p, smem);
}
__global__ __launch_bounds__(256) void k_attn_f(Params p) {
  attn_block(blockIdx.x, threadIdx.x, p);
}
__global__ __launch_bounds__(256) void k_proj_f(Params p) {
  __shared__ unsigned short smem[16384];
  proj_tile(blockIdx.x, blockIdx.y, blockIdx.z, threadIdx.x, p, smem);
}
template <bool FINAL>
__global__ __launch_bounds__(256) void k_hw_f(Params p) {
  __shared__ unsigned short smem[16384];
  hw_tile<FINAL>(blockIdx.x, blockIdx.y, blockIdx.z, threadIdx.x, p, smem);
}

// ---------------------------------------------------------------------------
extern "C" void kernel_launch(void* const* d_in, const int* in_sizes, int n_in,
                              void* d_out, int out_size, void* d_ws, size_t ws_size,
                              hipStream_t stream) {
  unsigned short* ws = (unsigned short*)d_ws;

  const size_t NIN  = (size_t)B_ * S2_ * D_;       // 4,259,840
  const size_t NQKV = (size_t)B_ * S2_ * 3072;     // 25,559,040
  const size_t MS   = (size_t)B_ * S_ * D_;        // 4,194,304
  const size_t DD   = (size_t)D_ * D_;             // 262,144
  const size_t LHW  = (size_t)1024 * 512;          // 524,288

  Params p;
  p.x    = (const float*)d_in[0];
  p.lW   = (const float*)d_in[1];
  p.lb   = (const float*)d_in[2];
  p.rW   = (const float*)d_in[3];
  p.rb   = (const float*)d_in[4];
  p.lpad = (const float*)d_in[5];
  p.rpad = (const float*)d_in[6];
  p.lw   = (const float*)d_in[7];
  p.rw   = (const float*)d_in[8];
  p.lhwW = (const float*)d_in[9];
  p.lhwb = (const float*)d_in[10];
  p.rhwW = (const float*)d_in[11];
  p.rhwb = (const float*)d_in[12];
  p.out  = (float*)d_out;

  p.nin   = ws;
  p.qkv   = p.nin + NIN;
  p.ctx   = p.qkv + NQKV;
  p.hwx   = p.ctx + 2 * MS;
  p.hwy   = p.hwx + 2 * MS;
  p.WTall = p.hwy + 2 * MS;
  p.WTp   = p.WTall + 6 * DD;
  p.hWT   = p.WTp + 2 * DD;
  p.qkvbias = (float*)(p.hWT + 4 * LHW);

  // Size the cooperative grid from the runtime's own occupancy model.
  int occ = 0;
  hipError_t qe = hipOccupancyMaxActiveBlocksPerMultiprocessor(
      &occ, k_mega, 256, 0);
  int grid = 0;
  if (qe == hipSuccess && occ > 0) {
    grid = occ * 256;                  // 256 CUs on MI355X
    if (grid > 512) grid = 512;        // 2 blocks/CU is all we need
  }

  hipError_t le = hipErrorUnknown;
  if (grid > 0) {
    void* args[] = {&p};
    le = hipLaunchCooperativeKernel((const void*)k_mega, dim3(grid), dim3(256),
                                    args, 0, stream);
  }

  if (le != hipSuccess) {
    // fallback: identical 6-dispatch pipeline
    k_prep_f<<<6188, 256, 0, stream>>>(p);
    k_qkv_f<<<dim3(24, 65), 256, 0, stream>>>(p);
    k_attn_f<<<4096, 256, 0, stream>>>(p);
    k_proj_f<<<dim3(4, 64, 2), 256, 0, stream>>>(p);
    k_hw_f<false><<<dim3(8, 64, 2), 256, 0, stream>>>(p);
    k_hw_f<true><<<dim3(8, 64, 2), 256, 0, stream>>>(p);
  }
}